// Round 7
// baseline (898.145 us; speedup 1.0000x reference)
//
#include <hip/hip_runtime.h>
#include <hip/hip_bf16.h>

// BasicGCN: out = log_softmax( A @ (relu(A @ x @ W1 + b1) @ W2) + b2 )
// R7: agg1 restructured into 8 feature-sliced passes. Evidence: random gathers
// are request-rate bound (~105-115 G sectors/s across R1-R6 configs). Each pass
// gathers from a 3.2MB column-block sub-table (fits per-XCD 4MB L2 -> hits),
// with nontemporal src/ax streams to protect residency. CSR payload shrunk to
// src-only (weights re-gathered from L2-hot 400KB fused dinv*scale tables).

typedef __bf16 bf16;
typedef bf16 bf16x4 __attribute__((ext_vector_type(4)));
typedef bf16 bf16x8 __attribute__((ext_vector_type(8)));
typedef float f32x4 __attribute__((ext_vector_type(4)));
typedef signed char s8;
typedef s8 s8x4 __attribute__((ext_vector_type(4)));
typedef s8 s8x8 __attribute__((ext_vector_type(8)));

#define NBLK 256  // edge-chunk blocks for bucketing passes

// ---------------- pass 1: per-block bucket histogram (LDS) ----------------
__global__ __launch_bounds__(256) void k_b1(const int* __restrict__ edge, int E, int chunk,
                                            int NB, int* __restrict__ gcnt) {
    __shared__ int cnt[512];
    int tid = threadIdx.x;
    for (int i = tid; i < NB; i += 256) cnt[i] = 0;
    __syncthreads();
    int s = blockIdx.x * chunk, e = min(s + chunk, E);
    for (int i = s + tid; i < e; i += 256) atomicAdd(&cnt[edge[E + i] >> 9], 1);
    __syncthreads();
    for (int i = tid; i < NB; i += 256) gcnt[blockIdx.x * NB + i] = cnt[i];
}

// ---------------- pass 2a: bucket starts ----------------
__global__ void k_b2(const int* __restrict__ gcnt, int NB, int E, int* __restrict__ bstart) {
    __shared__ int col[256];
    int k = threadIdx.x;
    int sum = 0;
    if (k < NB)
        for (int b = 0; b < NBLK; ++b) sum += gcnt[b * NB + k];
    col[k] = sum;
    __syncthreads();
    for (int o = 1; o < 256; o <<= 1) {
        int v = (k >= o) ? col[k - o] : 0;
        __syncthreads();
        col[k] += v;
        __syncthreads();
    }
    if (k < NB) bstart[k] = col[k] - sum;
    if (k == 0) bstart[NB] = E;
}

// ---------------- pass 2b: per-(block,bucket) bases ----------------
__global__ void k_b2b(int* __restrict__ gcnt, int NB, const int* __restrict__ bstart) {
    __shared__ int col[256];
    int b = threadIdx.x;  // NBLK == 256
    int k = blockIdx.x;
    int v = gcnt[b * NB + k];
    col[b] = v;
    __syncthreads();
    for (int o = 1; o < 256; o <<= 1) {
        int t = (b >= o) ? col[b - o] : 0;
        __syncthreads();
        col[b] += t;
        __syncthreads();
    }
    gcnt[b * NB + k] = bstart[k] + col[b] - v;
}

// ---------------- pass 3: scatter edges into bucket-grouped ebuf ----------------
// packed: src (17 bits) | (dst & 511) << 17
__global__ __launch_bounds__(256) void k_b3(const int* __restrict__ edge, int E, int chunk,
                                            int NB, const int* __restrict__ base,
                                            int* __restrict__ ebuf) {
    __shared__ int cnt[512];
    __shared__ int bs[512];
    int tid = threadIdx.x;
    for (int i = tid; i < NB; i += 256) {
        cnt[i] = 0;
        bs[i] = base[blockIdx.x * NB + i];
    }
    __syncthreads();
    int s = blockIdx.x * chunk, e = min(s + chunk, E);
    for (int i = s + tid; i < e; i += 256) {
        int sv = edge[i], dv = edge[E + i];
        int k = dv >> 9;
        int r = atomicAdd(&cnt[k], 1);  // LDS atomic
        ebuf[bs[k] + r] = sv | ((dv & 511) << 17);
    }
}

// ---------------- pass 4: per-bucket degree histogram -> dense deg ----------------
__global__ __launch_bounds__(256) void k_b4(const int* __restrict__ ebuf,
                                            const int* __restrict__ bstart, int n,
                                            int* __restrict__ deg) {
    __shared__ int cnt[512];
    int tid = threadIdx.x;
    int k = blockIdx.x;
    cnt[tid] = 0;
    cnt[tid + 256] = 0;
    __syncthreads();
    int s = bstart[k], e = bstart[k + 1];
    for (int i = s + tid; i < e; i += 256) atomicAdd(&cnt[(ebuf[i] >> 17) & 511], 1);
    __syncthreads();
    int base = k << 9;
    if (base + tid < n) deg[base + tid] = cnt[tid];
    if (base + 256 + tid < n) deg[base + 256 + tid] = cnt[tid + 256];
}

// ---------------- parallel scan over deg ----------------
__global__ void k_scan1(const int* __restrict__ deg, int n, int* __restrict__ bsum) {
    __shared__ int red[256];
    int base = blockIdx.x * 1024;
    int tid = threadIdx.x;
    int s = 0;
#pragma unroll
    for (int j = 0; j < 4; ++j) {
        int i = base + j * 256 + tid;
        if (i < n) s += deg[i];
    }
    red[tid] = s;
    __syncthreads();
    for (int o = 128; o > 0; o >>= 1) {
        if (tid < o) red[tid] += red[tid + o];
        __syncthreads();
    }
    if (tid == 0) bsum[blockIdx.x] = red[0];
}

__global__ void k_scan2(int* __restrict__ bsum, int nb, int E, int* __restrict__ off, int n) {
    if (threadIdx.x == 0) {
        int run = 0;
        for (int b = 0; b < nb; ++b) { int v = bsum[b]; bsum[b] = run; run += v; }
        off[n] = E;
    }
}

__global__ void k_scan3(const int* __restrict__ deg, int n, const int* __restrict__ bbase,
                        int* __restrict__ off, float* __restrict__ dinv) {
    __shared__ int red[256];
    int base = blockIdx.x * 1024;
    int tid = threadIdx.x;
    int d[4], t = 0;
#pragma unroll
    for (int j = 0; j < 4; ++j) {
        int i = base + tid * 4 + j;
        d[j] = (i < n) ? deg[i] : 0;
        t += d[j];
    }
    red[tid] = t;
    __syncthreads();
    for (int o = 1; o < 256; o <<= 1) {
        int v = (tid >= o) ? red[tid - o] : 0;
        __syncthreads();
        red[tid] += v;
        __syncthreads();
    }
    int run = bbase[blockIdx.x] + red[tid] - t;  // exclusive prefix
#pragma unroll
    for (int j = 0; j < 4; ++j) {
        int i = base + tid * 4 + j;
        if (i < n) {
            off[i] = run;
            dinv[i] = rsqrtf((float)(d[j] + 1));  // +1 self-loop
            run += d[j];
        }
    }
}

// ---------------- pass 6: per-bucket CSR fill (src only) ----------------
__global__ __launch_bounds__(256) void k_b6(const int* __restrict__ ebuf,
                                            const int* __restrict__ bstart,
                                            const int* __restrict__ off, int n,
                                            int* __restrict__ csr_src) {
    __shared__ int cnt[512];
    __shared__ int offl[512];
    int tid = threadIdx.x;
    int k = blockIdx.x;
    int base = k << 9;
    cnt[tid] = 0;
    cnt[tid + 256] = 0;
    offl[tid] = (base + tid < n) ? off[base + tid] : 0;
    offl[tid + 256] = (base + 256 + tid < n) ? off[base + 256 + tid] : 0;
    __syncthreads();
    int s = bstart[k], e = bstart[k + 1];
    for (int i = s + tid; i < e; i += 256) {
        int pk = ebuf[i];
        int node = (pk >> 17) & 511;
        int r = atomicAdd(&cnt[node], 1);  // LDS atomic
        csr_src[offl[node] + r] = pk & 0x1ffff;
    }
}

// ---------------- x -> column-blocked int8 sub-tables + wsrc=scale*dinv ----------------
// xqc layout: [f][n][32], f = col>>5
__global__ __launch_bounds__(256) void k_quant(const float* __restrict__ x,
                                               const float* __restrict__ dinv,
                                               s8* __restrict__ xqc,
                                               float* __restrict__ wsrc, int n) {
    int row = blockIdx.x * 4 + (threadIdx.x >> 6);
    int lane = threadIdx.x & 63;
    if (row >= n) return;
    f32x4 v = ((const f32x4*)x)[(size_t)row * 64 + lane];
    float m = fmaxf(fmaxf(fabsf(v[0]), fabsf(v[1])), fmaxf(fabsf(v[2]), fabsf(v[3])));
    for (int o = 32; o > 0; o >>= 1) m = fmaxf(m, __shfl_xor(m, o));
    m = fmaxf(m, 1e-20f);
    float inv = 127.0f / m;
    int b0 = __float2int_rn(v[0] * inv) & 255;
    int b1 = __float2int_rn(v[1] * inv) & 255;
    int b2 = __float2int_rn(v[2] * inv) & 255;
    int b3 = __float2int_rn(v[3] * inv) & 255;
    int f = lane >> 3;          // col block = (lane*4)>>5
    int pos = (lane & 7) * 4;   // within block
    *(int*)(xqc + ((size_t)f * n + row) * 32 + pos) = b0 | (b1 << 8) | (b2 << 16) | (b3 << 24);
    if (lane == 0) wsrc[row] = (m / 127.0f) * dinv[row];
}

// ---------------- tb (n x 64 bf16) -> int8 + tw=tscale*dinv ----------------
__global__ __launch_bounds__(256) void k_quant2(const bf16* __restrict__ tb,
                                                const float* __restrict__ dinv,
                                                s8* __restrict__ tq,
                                                float* __restrict__ tw, int n) {
    int t = blockIdx.x * 256 + threadIdx.x;
    int row = t >> 3;
    int l8 = t & 7;
    if (row >= n) return;
    bf16x8 v = ((const bf16x8*)tb)[(size_t)row * 8 + l8];
    float f[8], m = 0.0f;
#pragma unroll
    for (int j = 0; j < 8; ++j) { f[j] = (float)v[j]; m = fmaxf(m, fabsf(f[j])); }
    for (int o = 4; o > 0; o >>= 1) m = fmaxf(m, __shfl_xor(m, o));
    m = fmaxf(m, 1e-20f);
    float inv = 127.0f / m;
    int lo = 0, hi = 0;
#pragma unroll
    for (int j = 0; j < 4; ++j) lo |= (__float2int_rn(f[j] * inv) & 255) << (8 * j);
#pragma unroll
    for (int j = 0; j < 4; ++j) hi |= (__float2int_rn(f[4 + j] * inv) & 255) << (8 * j);
    ((int2*)tq)[(size_t)row * 8 + l8] = make_int2(lo, hi);
    if (l8 == 0) tw[row] = (m / 127.0f) * dinv[row];
}

// ---------------- W (KxNC fp32) -> Wt (NCxK bf16) ----------------
__global__ void k_wt(const float* __restrict__ W, bf16* __restrict__ Wt, int NC) {
    int nc = blockIdx.x;
    int k = threadIdx.x;
    Wt[nc * 256 + k] = (bf16)W[k * NC + nc];
}

// ---------------- agg1 pass: ax[:, fbase:fbase+32] from 3.2MB sub-table ----------------
// 8 lanes/row, 4B/lane, unroll 8. src stream + ax writes nontemporal.
__global__ __launch_bounds__(256) void k_agg1p(const s8* __restrict__ xsub,
                                               const float* __restrict__ wsrc,
                                               const int* __restrict__ off,
                                               const int* __restrict__ csr_src,
                                               const float* __restrict__ dinv,
                                               bf16* __restrict__ ax, int n, int fbase) {
    int t = blockIdx.x * 256 + threadIdx.x;
    int node = t >> 3;
    int l8 = t & 7;
    if (node >= n) return;
    int s0 = off[node], s1 = off[node + 1];
    float dv = dinv[node];
    const s8x4* X = (const s8x4*)xsub;
    s8x4 xs = X[(size_t)node * 8 + l8];
    float wn = wsrc[node];
    float a[4];
#pragma unroll
    for (int j = 0; j < 4; ++j) a[j] = wn * (float)xs[j];
    int e = s0;
    for (; e + 8 <= s1; e += 8) {
        int sv[8];
#pragma unroll
        for (int q = 0; q < 8; ++q) sv[q] = __builtin_nontemporal_load(csr_src + e + q);
        float w[8];
#pragma unroll
        for (int q = 0; q < 8; ++q) w[q] = wsrc[sv[q]];
        s8x4 xv[8];
#pragma unroll
        for (int q = 0; q < 8; ++q) xv[q] = X[(size_t)sv[q] * 8 + l8];
#pragma unroll
        for (int q = 0; q < 8; ++q) {
#pragma unroll
            for (int j = 0; j < 4; ++j) a[j] += w[q] * (float)xv[q][j];
        }
    }
    for (; e < s1; ++e) {
        int sv = __builtin_nontemporal_load(csr_src + e);
        float w = wsrc[sv];
        s8x4 xv = X[(size_t)sv * 8 + l8];
#pragma unroll
        for (int j = 0; j < 4; ++j) a[j] += w * (float)xv[j];
    }
    bf16x4 o;
#pragma unroll
    for (int j = 0; j < 4; ++j) o[j] = (bf16)(a[j] * dv);
    __builtin_nontemporal_store(o, (bf16x4*)(ax + (size_t)node * 256 + fbase + l8 * 4));
}

// ---------------- bf16 MFMA GEMM: C[n x NC] = A[n x 256] @ Bt[NC x 256]^T ----------------
template <bool BIAS_RELU>
__global__ __launch_bounds__(256) void k_gemm(const bf16* __restrict__ A,
                                              const bf16* __restrict__ Bt,
                                              const float* __restrict__ bias,
                                              bf16* __restrict__ C, int n, int NC) {
    __shared__ __align__(16) bf16 As[4 * 64 * 8];
    __shared__ __align__(16) bf16 Bs[4 * 64 * 8];
    int tid = threadIdx.x;
    int bm = blockIdx.x * 64;
    int bn = blockIdx.y * 64;
    int w = tid >> 6, lane = tid & 63;
    int wm = w >> 1, wn = w & 1;

    int r = tid >> 2;
    int cq = tid & 3;
    int lds_idx = (((r >> 4) * 64) + cq * 16 + (r & 15)) * 8;
    int arow = bm + r; if (arow > n - 1) arow = n - 1;
    int brow = bn + r;

    f32x4 acc[2][2] = {};

    for (int k0 = 0; k0 < 256; k0 += 32) {
        __syncthreads();
        uint4 av = *(const uint4*)(A + (size_t)arow * 256 + k0 + cq * 8);
        uint4 bv = *(const uint4*)(Bt + (size_t)brow * 256 + k0 + cq * 8);
        *(uint4*)(As + lds_idx) = av;
        *(uint4*)(Bs + lds_idx) = bv;
        __syncthreads();
#pragma unroll
        for (int i = 0; i < 2; ++i) {
            bf16x8 af = *(const bf16x8*)(As + ((wm * 2 + i) * 64 + lane) * 8);
#pragma unroll
            for (int j = 0; j < 2; ++j) {
                bf16x8 bfr = *(const bf16x8*)(Bs + ((wn * 2 + j) * 64 + lane) * 8);
                acc[i][j] = __builtin_amdgcn_mfma_f32_16x16x32_bf16(af, bfr, acc[i][j], 0, 0, 0);
            }
        }
    }

    int colb = lane & 15, rowq = lane >> 4;
#pragma unroll
    for (int i = 0; i < 2; ++i) {
#pragma unroll
        for (int j = 0; j < 2; ++j) {
            int col = bn + wn * 32 + j * 16 + colb;
#pragma unroll
            for (int rr = 0; rr < 4; ++rr) {
                int row = bm + wm * 32 + i * 16 + rowq * 4 + rr;
                if (row < n) {
                    float v = acc[i][j][rr];
                    if constexpr (BIAS_RELU) {
                        v += bias[col];
                        v = v > 0.0f ? v : 0.0f;
                    }
                    C[(size_t)row * NC + col] = (bf16)v;
                }
            }
        }
    }
}

// ---------------- agg2 (int8 table, src-only CSR) + bias + log_softmax ----------------
__global__ __launch_bounds__(256) void k_agg2(const s8* __restrict__ tq,
                                              const float* __restrict__ tw,
                                              const int* __restrict__ off,
                                              const int* __restrict__ csr_src,
                                              const float* __restrict__ dinv,
                                              const float* __restrict__ b2,
                                              float* __restrict__ out, int n) {
    int wv = blockIdx.x * 4 + (threadIdx.x >> 6);
    int lane = threadIdx.x & 63;
    int node = wv * 8 + (lane >> 3);
    int l8 = lane & 7;
    if (node >= n) return;
    int s0 = off[node], s1 = off[node + 1];
    float dv = dinv[node];
    const s8x8* T = (const s8x8*)tq;  // row = 8 x s8x8 (64B)
    s8x8 ts = T[(size_t)node * 8 + l8];
    float ws = tw[node];
    float a[8];
#pragma unroll
    for (int j = 0; j < 8; ++j) a[j] = ws * (float)ts[j];
    int e = s0;
    for (; e + 4 <= s1; e += 4) {
        int sv[4];
#pragma unroll
        for (int q = 0; q < 4; ++q) sv[q] = __builtin_nontemporal_load(csr_src + e + q);
        float w[4];
#pragma unroll
        for (int q = 0; q < 4; ++q) w[q] = tw[sv[q]];
        s8x8 tv[4];
#pragma unroll
        for (int q = 0; q < 4; ++q) tv[q] = T[(size_t)sv[q] * 8 + l8];
#pragma unroll
        for (int q = 0; q < 4; ++q) {
#pragma unroll
            for (int j = 0; j < 8; ++j) a[j] += w[q] * (float)tv[q][j];
        }
    }
    for (; e < s1; ++e) {
        int sv = __builtin_nontemporal_load(csr_src + e);
        float w = tw[sv];
        s8x8 tv = T[(size_t)sv * 8 + l8];
#pragma unroll
        for (int j = 0; j < 8; ++j) a[j] += w * (float)tv[j];
    }
    const float4* B2 = (const float4*)b2;
    float4 bv0 = B2[l8 * 2], bv1 = B2[l8 * 2 + 1];
    a[0] = a[0] * dv + bv0.x; a[1] = a[1] * dv + bv0.y;
    a[2] = a[2] * dv + bv0.z; a[3] = a[3] * dv + bv0.w;
    a[4] = a[4] * dv + bv1.x; a[5] = a[5] * dv + bv1.y;
    a[6] = a[6] * dv + bv1.z; a[7] = a[7] * dv + bv1.w;
    float m = a[0];
#pragma unroll
    for (int j = 1; j < 8; ++j) m = fmaxf(m, a[j]);
    for (int o = 4; o > 0; o >>= 1) m = fmaxf(m, __shfl_xor(m, o));
    float s = 0.0f;
#pragma unroll
    for (int j = 0; j < 8; ++j) s += __expf(a[j] - m);
    for (int o = 4; o > 0; o >>= 1) s += __shfl_xor(s, o);
    float ls = m + __logf(s);
    f32x4 o0, o1;
    o0[0] = a[0] - ls; o0[1] = a[1] - ls; o0[2] = a[2] - ls; o0[3] = a[3] - ls;
    o1[0] = a[4] - ls; o1[1] = a[5] - ls; o1[2] = a[6] - ls; o1[3] = a[7] - ls;
    f32x4* O = (f32x4*)out;  // row = 16 x f32x4
    O[(size_t)node * 16 + l8 * 2] = o0;
    O[(size_t)node * 16 + l8 * 2 + 1] = o1;
}

extern "C" void kernel_launch(void* const* d_in, const int* in_sizes, int n_in,
                              void* d_out, int out_size, void* d_ws, size_t ws_size,
                              hipStream_t stream) {
    const float* x   = (const float*)d_in[0];
    const int*  edge = (const int*)d_in[1];
    const float* W1  = (const float*)d_in[2];
    const float* b1  = (const float*)d_in[3];
    const float* W2  = (const float*)d_in[4];
    const float* b2  = (const float*)d_in[5];
    float* out = (float*)d_out;

    int n = in_sizes[0] / 256;   // 100000
    int E = in_sizes[1] / 2;     // 3200000
    int nb = (n + 1023) / 1024;  // scan chunks
    int NB = (n + 511) >> 9;     // node buckets (512 each); requires n < 131072
    int chunk = (E + NBLK - 1) / NBLK;

    char* ws = (char*)d_ws;
    auto alloc = [&](size_t bytes) -> char* {
        char* p = ws;
        ws += (bytes + 255) & ~(size_t)255;
        return p;
    };
    int*   gcnt    = (int*)alloc((size_t)NBLK * NB * 4);
    int*   bstart  = (int*)alloc((size_t)(NB + 1) * 4);
    int*   ebuf    = (int*)alloc((size_t)E * 4);
    int*   deg     = (int*)alloc((size_t)n * 4);
    float* dinv    = (float*)alloc((size_t)n * 4);
    int*   off     = (int*)alloc((size_t)(n + 1) * 4);
    int*   bsum    = (int*)alloc((size_t)nb * 4);
    int*   csr_src = (int*)alloc((size_t)E * 4);
    s8*    xqc     = (s8*)alloc((size_t)n * 256);
    float* wsrc    = (float*)alloc((size_t)n * 4);
    bf16*  ax      = (bf16*)alloc((size_t)n * 256 * 2);
    bf16*  h1      = (bf16*)alloc((size_t)n * 256 * 2);
    bf16*  tb      = (bf16*)alloc((size_t)n * 64 * 2);
    s8*    tq      = (s8*)alloc((size_t)n * 64);
    float* tw      = (float*)alloc((size_t)n * 4);
    bf16*  W1t     = (bf16*)alloc(256 * 256 * 2);
    bf16*  W2t     = (bf16*)alloc(64 * 256 * 2);

    // --- CSR build (no global atomics) ---
    k_b1<<<NBLK, 256, 0, stream>>>(edge, E, chunk, NB, gcnt);
    k_b2<<<1, 256, 0, stream>>>(gcnt, NB, E, bstart);
    k_b2b<<<NB, 256, 0, stream>>>(gcnt, NB, bstart);
    k_b3<<<NBLK, 256, 0, stream>>>(edge, E, chunk, NB, gcnt, ebuf);
    k_b4<<<NB, 256, 0, stream>>>(ebuf, bstart, n, deg);
    k_scan1<<<nb, 256, 0, stream>>>(deg, n, bsum);
    k_scan2<<<1, 64, 0, stream>>>(bsum, nb, E, off, n);
    k_scan3<<<nb, 256, 0, stream>>>(deg, n, bsum, off, dinv);
    k_b6<<<NB, 256, 0, stream>>>(ebuf, bstart, off, n, csr_src);

    // --- feature prep (quant needs dinv -> after scan3) ---
    k_quant<<<(n + 3) / 4, 256, 0, stream>>>(x, dinv, xqc, wsrc, n);
    k_wt<<<256, 256, 0, stream>>>(W1, W1t, 256);
    k_wt<<<64, 256, 0, stream>>>(W2, W2t, 64);

    // --- layer 1: 8 feature-sliced aggregation passes, then GEMM ---
    int g1p = (n * 8 + 255) / 256;
    for (int f = 0; f < 8; ++f) {
        k_agg1p<<<g1p, 256, 0, stream>>>(xqc + (size_t)f * n * 32, wsrc, off, csr_src,
                                         dinv, ax, n, f * 32);
    }
    dim3 g1((n + 63) / 64, 4);
    k_gemm<true><<<g1, 256, 0, stream>>>(ax, W1t, b1, h1, n, 256);

    // --- layer 2 ---
    dim3 g2((n + 63) / 64, 1);
    k_gemm<false><<<g2, 256, 0, stream>>>(h1, W2t, nullptr, tb, n, 64);
    k_quant2<<<(n * 8 + 255) / 256, 256, 0, stream>>>(tb, dinv, tq, tw, n);
    k_agg2<<<(n + 31) / 32, 256, 0, stream>>>(tq, tw, off, csr_src, dinv, b2, out, n);
}

// Round 8
// 553.506 us; speedup vs baseline: 1.6226x; 1.6226x over previous
//
#include <hip/hip_runtime.h>
#include <hip/hip_bf16.h>

// BasicGCN: out = log_softmax( A @ (relu(A @ x @ W1 + b1) @ W2) + b2 )
// R8: revert to R6 gather structure (R7's feature slicing multiplied random
// requests -> 898us). New: k_b45 merges deg-hist + global scan into bucket-
// local scan (off = bstart[k] + local scan); k_gemmp row-panel GEMM reads A
// once (old grid.y=4 re-read A 4x).

typedef __bf16 bf16;
typedef bf16 bf16x4 __attribute__((ext_vector_type(4)));
typedef bf16 bf16x8 __attribute__((ext_vector_type(8)));
typedef float f32x4 __attribute__((ext_vector_type(4)));
typedef signed char s8;
typedef s8 s8x8 __attribute__((ext_vector_type(8)));

#define NBLK 256  // edge-chunk blocks for bucketing passes

// ---------------- pass 1: per-block bucket histogram (LDS) ----------------
__global__ __launch_bounds__(256) void k_b1(const int* __restrict__ edge, int E, int chunk,
                                            int NB, int* __restrict__ gcnt) {
    __shared__ int cnt[512];
    int tid = threadIdx.x;
    for (int i = tid; i < NB; i += 256) cnt[i] = 0;
    __syncthreads();
    int s = blockIdx.x * chunk, e = min(s + chunk, E);
    for (int i = s + tid; i < e; i += 256) atomicAdd(&cnt[edge[E + i] >> 9], 1);
    __syncthreads();
    for (int i = tid; i < NB; i += 256) gcnt[blockIdx.x * NB + i] = cnt[i];
}

// ---------------- pass 2a: bucket starts ----------------
__global__ void k_b2(const int* __restrict__ gcnt, int NB, int E, int* __restrict__ bstart) {
    __shared__ int col[256];
    int k = threadIdx.x;
    int sum = 0;
    if (k < NB)
        for (int b = 0; b < NBLK; ++b) sum += gcnt[b * NB + k];
    col[k] = sum;
    __syncthreads();
    for (int o = 1; o < 256; o <<= 1) {
        int v = (k >= o) ? col[k - o] : 0;
        __syncthreads();
        col[k] += v;
        __syncthreads();
    }
    if (k < NB) bstart[k] = col[k] - sum;
    if (k == 0) bstart[NB] = E;
}

// ---------------- pass 2b: per-(block,bucket) bases ----------------
__global__ void k_b2b(int* __restrict__ gcnt, int NB, const int* __restrict__ bstart) {
    __shared__ int col[256];
    int b = threadIdx.x;  // NBLK == 256
    int k = blockIdx.x;
    int v = gcnt[b * NB + k];
    col[b] = v;
    __syncthreads();
    for (int o = 1; o < 256; o <<= 1) {
        int t = (b >= o) ? col[b - o] : 0;
        __syncthreads();
        col[b] += t;
        __syncthreads();
    }
    gcnt[b * NB + k] = bstart[k] + col[b] - v;
}

// ---------------- pass 3: scatter edges into bucket-grouped ebuf ----------------
// packed: src (17 bits) | (dst & 511) << 17
__global__ __launch_bounds__(256) void k_b3(const int* __restrict__ edge, int E, int chunk,
                                            int NB, const int* __restrict__ base,
                                            int* __restrict__ ebuf) {
    __shared__ int cnt[512];
    __shared__ int bs[512];
    int tid = threadIdx.x;
    for (int i = tid; i < NB; i += 256) {
        cnt[i] = 0;
        bs[i] = base[blockIdx.x * NB + i];
    }
    __syncthreads();
    int s = blockIdx.x * chunk, e = min(s + chunk, E);
    for (int i = s + tid; i < e; i += 256) {
        int sv = edge[i], dv = edge[E + i];
        int k = dv >> 9;
        int r = atomicAdd(&cnt[k], 1);  // LDS atomic
        ebuf[bs[k] + r] = sv | ((dv & 511) << 17);
    }
}

// ---------------- pass 4+5 merged: per-bucket hist + local scan -> off, dinv ----------------
// off[node] = bstart[bucket] + exclusive_scan_within_bucket(deg)
__global__ __launch_bounds__(256) void k_b45(const int* __restrict__ ebuf,
                                             const int* __restrict__ bstart, int n, int E,
                                             int NB, int* __restrict__ off,
                                             float* __restrict__ dinv) {
    __shared__ int cnt[512];
    __shared__ int red[256];
    int tid = threadIdx.x;
    int k = blockIdx.x;
    cnt[tid] = 0;
    cnt[tid + 256] = 0;
    __syncthreads();
    int s = bstart[k], e = bstart[k + 1];
    for (int i = s + tid; i < e; i += 256) atomicAdd(&cnt[(ebuf[i] >> 17) & 511], 1);
    __syncthreads();
    int c0 = cnt[tid * 2], c1 = cnt[tid * 2 + 1];
    int sum = c0 + c1;
    red[tid] = sum;
    __syncthreads();
    for (int o = 1; o < 256; o <<= 1) {
        int v = (tid >= o) ? red[tid - o] : 0;
        __syncthreads();
        red[tid] += v;
        __syncthreads();
    }
    int ex = red[tid] - sum;  // exclusive prefix over pairs
    int base = k << 9;
    int g0 = base + tid * 2, g1 = g0 + 1;
    int o0 = s + ex, o1 = s + ex + c0;
    if (g0 < n) { off[g0] = o0; dinv[g0] = rsqrtf((float)(c0 + 1)); }
    else if (g0 == n) off[g0] = o0;
    if (g1 < n) { off[g1] = o1; dinv[g1] = rsqrtf((float)(c1 + 1)); }
    else if (g1 == n) off[g1] = o1;
    if (k == NB - 1 && tid == 0) off[n] = E;
}

// ---------------- pass 6: per-bucket CSR fill (LDS ranks, LDS off) ----------------
__global__ __launch_bounds__(256) void k_b6(const int* __restrict__ ebuf,
                                            const int* __restrict__ bstart,
                                            const int* __restrict__ off,
                                            const float* __restrict__ dinv, int n,
                                            int2* __restrict__ pair) {
    __shared__ int cnt[512];
    __shared__ int offl[512];
    int tid = threadIdx.x;
    int k = blockIdx.x;
    int base = k << 9;
    cnt[tid] = 0;
    cnt[tid + 256] = 0;
    offl[tid] = (base + tid < n) ? off[base + tid] : 0;
    offl[tid + 256] = (base + 256 + tid < n) ? off[base + 256 + tid] : 0;
    __syncthreads();
    int s = bstart[k], e = bstart[k + 1];
    for (int i = s + tid; i < e; i += 256) {
        int pk = ebuf[i];
        int sv = pk & 0x1ffff;
        int node = (pk >> 17) & 511;
        int r = atomicAdd(&cnt[node], 1);  // LDS atomic
        pair[offl[node] + r] = make_int2(sv, __float_as_int(dinv[sv]));
    }
}

// ---------------- x -> per-row-scaled int8 (one wave per row) ----------------
__global__ __launch_bounds__(256) void k_quant(const float* __restrict__ x,
                                               s8* __restrict__ xq,
                                               float* __restrict__ scale, int n) {
    int row = blockIdx.x * 4 + (threadIdx.x >> 6);
    int lane = threadIdx.x & 63;
    if (row >= n) return;
    f32x4 v = ((const f32x4*)x)[(size_t)row * 64 + lane];
    float m = fmaxf(fmaxf(fabsf(v[0]), fabsf(v[1])), fmaxf(fabsf(v[2]), fabsf(v[3])));
    for (int o = 32; o > 0; o >>= 1) m = fmaxf(m, __shfl_xor(m, o));
    m = fmaxf(m, 1e-20f);
    float inv = 127.0f / m;
    int b0 = __float2int_rn(v[0] * inv) & 255;
    int b1 = __float2int_rn(v[1] * inv) & 255;
    int b2 = __float2int_rn(v[2] * inv) & 255;
    int b3 = __float2int_rn(v[3] * inv) & 255;
    ((int*)xq)[(size_t)row * 64 + lane] = b0 | (b1 << 8) | (b2 << 16) | (b3 << 24);
    if (lane == 0) scale[row] = m / 127.0f;
}

// ---------------- tb (n x 64 bf16) -> per-row int8 + scale ----------------
__global__ __launch_bounds__(256) void k_quant2(const bf16* __restrict__ tb,
                                                s8* __restrict__ tq,
                                                float* __restrict__ tscale, int n) {
    int t = blockIdx.x * 256 + threadIdx.x;
    int row = t >> 3;
    int l8 = t & 7;
    if (row >= n) return;
    bf16x8 v = ((const bf16x8*)tb)[(size_t)row * 8 + l8];
    float f[8], m = 0.0f;
#pragma unroll
    for (int j = 0; j < 8; ++j) { f[j] = (float)v[j]; m = fmaxf(m, fabsf(f[j])); }
    for (int o = 4; o > 0; o >>= 1) m = fmaxf(m, __shfl_xor(m, o));
    m = fmaxf(m, 1e-20f);
    float inv = 127.0f / m;
    int lo = 0, hi = 0;
#pragma unroll
    for (int j = 0; j < 4; ++j) lo |= (__float2int_rn(f[j] * inv) & 255) << (8 * j);
#pragma unroll
    for (int j = 0; j < 4; ++j) hi |= (__float2int_rn(f[4 + j] * inv) & 255) << (8 * j);
    ((int2*)tq)[(size_t)row * 8 + l8] = make_int2(lo, hi);
    if (l8 == 0) tscale[row] = m / 127.0f;
}

// ---------------- W (KxNC fp32) -> Wt (NCxK bf16) ----------------
__global__ void k_wt(const float* __restrict__ W, bf16* __restrict__ Wt, int NC) {
    int nc = blockIdx.x;
    int k = threadIdx.x;
    Wt[nc * 256 + k] = (bf16)W[k * NC + nc];
}

// ---------------- agg1: ax = A @ x (int8 table). 2 nodes/wave, 8B/lane, unroll 8 ----------------
__global__ __launch_bounds__(256) void k_agg1(const s8* __restrict__ xq,
                                              const float* __restrict__ scale,
                                              const int* __restrict__ off,
                                              const int2* __restrict__ pair,
                                              const float* __restrict__ dinv,
                                              bf16* __restrict__ ax, int n) {
    int wv = blockIdx.x * 4 + (threadIdx.x >> 6);
    int lane = threadIdx.x & 63;
    int node = wv * 2 + (lane >> 5);
    int l32 = lane & 31;
    if (node >= n) return;
    int s0 = off[node], s1 = off[node + 1];
    float dv = dinv[node];
    const s8x8* X = (const s8x8*)xq;
    s8x8 xs = X[(size_t)node * 32 + l32];
    float ws = dv * scale[node];
    float a[8];
#pragma unroll
    for (int j = 0; j < 8; ++j) a[j] = ws * (float)xs[j];
    int e = s0;
    for (; e + 8 <= s1; e += 8) {
        int2 p[8];
#pragma unroll
        for (int q = 0; q < 8; ++q) p[q] = pair[e + q];
        float sc[8];
#pragma unroll
        for (int q = 0; q < 8; ++q) sc[q] = scale[p[q].x];
        s8x8 t[8];
#pragma unroll
        for (int q = 0; q < 8; ++q) t[q] = X[(size_t)p[q].x * 32 + l32];
#pragma unroll
        for (int q = 0; q < 8; ++q) {
            float w = __int_as_float(p[q].y) * sc[q];
#pragma unroll
            for (int j = 0; j < 8; ++j) a[j] += w * (float)t[q][j];
        }
    }
    for (; e < s1; ++e) {
        int2 p = pair[e];
        float w = __int_as_float(p.y) * scale[p.x];
        s8x8 t = X[(size_t)p.x * 32 + l32];
#pragma unroll
        for (int j = 0; j < 8; ++j) a[j] += w * (float)t[j];
    }
    bf16x8 o;
#pragma unroll
    for (int j = 0; j < 8; ++j) o[j] = (bf16)(a[j] * dv);
    ((bf16x8*)ax)[(size_t)node * 32 + l32] = o;
}

// ---------------- row-panel GEMM (layer 1): C[n x 256] = A[n x 256] @ Bt^T, +bias+relu ----
// 64-row panel per block; A read once; per wave: 16 col-tiles, 17 ds_read : 16 MFMA.
__global__ __launch_bounds__(256) void k_gemmp(const bf16* __restrict__ A,
                                               const bf16* __restrict__ Bt,
                                               const float* __restrict__ bias,
                                               bf16* __restrict__ C, int n) {
    __shared__ __align__(16) bf16 As[4 * 64 * 8];    // 64 rows x 32 k
    __shared__ __align__(16) bf16 Bs[16 * 64 * 8];   // 256 N x 32 k
    int tid = threadIdx.x;
    int bm = blockIdx.x * 64;
    int w = tid >> 6, lane = tid & 63;

    int r = tid >> 2;
    int cq = tid & 3;
    int a_idx = (((r >> 4) * 64) + cq * 16 + (r & 15)) * 8;
    int arow = bm + r; if (arow > n - 1) arow = n - 1;

    f32x4 acc[16] = {};

    for (int k0 = 0; k0 < 256; k0 += 32) {
        __syncthreads();
        uint4 av = *(const uint4*)(A + (size_t)arow * 256 + k0 + cq * 8);
        *(uint4*)(As + a_idx) = av;
#pragma unroll
        for (int rep = 0; rep < 4; ++rep) {
            int r2 = rep * 64 + r;
            uint4 bv = *(const uint4*)(Bt + (size_t)r2 * 256 + k0 + cq * 8);
            *(uint4*)(Bs + (((r2 >> 4) * 64) + cq * 16 + (r2 & 15)) * 8) = bv;
        }
        __syncthreads();
        bf16x8 af = *(const bf16x8*)(As + (w * 64 + lane) * 8);
#pragma unroll
        for (int ct = 0; ct < 16; ++ct) {
            bf16x8 bfr = *(const bf16x8*)(Bs + (ct * 64 + lane) * 8);
            acc[ct] = __builtin_amdgcn_mfma_f32_16x16x32_bf16(af, bfr, acc[ct], 0, 0, 0);
        }
    }

    int colb = lane & 15, rowq = lane >> 4;
#pragma unroll
    for (int ct = 0; ct < 16; ++ct) {
        int col = ct * 16 + colb;
        float bv = bias[col];
#pragma unroll
        for (int rr = 0; rr < 4; ++rr) {
            int row = bm + w * 16 + rowq * 4 + rr;
            if (row < n) {
                float v = acc[ct][rr] + bv;
                C[(size_t)row * 256 + col] = (bf16)(v > 0.0f ? v : 0.0f);
            }
        }
    }
}

// ---------------- 64x64 GEMM (layer 2): C[n x 64] = A[n x 256] @ Bt[64 x 256]^T ----------------
__global__ __launch_bounds__(256) void k_gemm2(const bf16* __restrict__ A,
                                               const bf16* __restrict__ Bt,
                                               bf16* __restrict__ C, int n) {
    __shared__ __align__(16) bf16 As[4 * 64 * 8];
    __shared__ __align__(16) bf16 Bs[4 * 64 * 8];
    int tid = threadIdx.x;
    int bm = blockIdx.x * 64;
    int w = tid >> 6, lane = tid & 63;
    int wm = w >> 1, wn = w & 1;

    int r = tid >> 2;
    int cq = tid & 3;
    int lds_idx = (((r >> 4) * 64) + cq * 16 + (r & 15)) * 8;
    int arow = bm + r; if (arow > n - 1) arow = n - 1;

    f32x4 acc[2][2] = {};

    for (int k0 = 0; k0 < 256; k0 += 32) {
        __syncthreads();
        uint4 av = *(const uint4*)(A + (size_t)arow * 256 + k0 + cq * 8);
        uint4 bv = *(const uint4*)(Bt + (size_t)r * 256 + k0 + cq * 8);
        *(uint4*)(As + lds_idx) = av;
        *(uint4*)(Bs + lds_idx) = bv;
        __syncthreads();
#pragma unroll
        for (int i = 0; i < 2; ++i) {
            bf16x8 af = *(const bf16x8*)(As + ((wm * 2 + i) * 64 + lane) * 8);
#pragma unroll
            for (int j = 0; j < 2; ++j) {
                bf16x8 bfr = *(const bf16x8*)(Bs + ((wn * 2 + j) * 64 + lane) * 8);
                acc[i][j] = __builtin_amdgcn_mfma_f32_16x16x32_bf16(af, bfr, acc[i][j], 0, 0, 0);
            }
        }
    }

    int colb = lane & 15, rowq = lane >> 4;
#pragma unroll
    for (int i = 0; i < 2; ++i) {
#pragma unroll
        for (int j = 0; j < 2; ++j) {
            int col = wn * 32 + j * 16 + colb;
#pragma unroll
            for (int rr = 0; rr < 4; ++rr) {
                int row = bm + wm * 32 + i * 16 + rowq * 4 + rr;
                if (row < n) C[(size_t)row * 64 + col] = (bf16)acc[i][j][rr];
            }
        }
    }
}

// ---------------- agg2 (int8 table) + bias + log_softmax. 8 nodes/wave, 8 lanes/row ----------------
__global__ __launch_bounds__(256) void k_agg2(const s8* __restrict__ tq,
                                              const float* __restrict__ tscale,
                                              const int* __restrict__ off,
                                              const int2* __restrict__ pair,
                                              const float* __restrict__ dinv,
                                              const float* __restrict__ b2,
                                              float* __restrict__ out, int n) {
    int wv = blockIdx.x * 4 + (threadIdx.x >> 6);
    int lane = threadIdx.x & 63;
    int node = wv * 8 + (lane >> 3);
    int l8 = lane & 7;
    if (node >= n) return;
    int s0 = off[node], s1 = off[node + 1];
    float dv = dinv[node];
    const s8x8* T = (const s8x8*)tq;  // row = 8 x s8x8 (64B)
    s8x8 ts = T[(size_t)node * 8 + l8];
    float ws = dv * tscale[node];
    float a[8];
#pragma unroll
    for (int j = 0; j < 8; ++j) a[j] = ws * (float)ts[j];
    int e = s0;
    for (; e + 4 <= s1; e += 4) {
        int2 p[4];
#pragma unroll
        for (int q = 0; q < 4; ++q) p[q] = pair[e + q];
        float sc[4];
#pragma unroll
        for (int q = 0; q < 4; ++q) sc[q] = tscale[p[q].x];
        s8x8 tv[4];
#pragma unroll
        for (int q = 0; q < 4; ++q) tv[q] = T[(size_t)p[q].x * 8 + l8];
#pragma unroll
        for (int q = 0; q < 4; ++q) {
            float w = __int_as_float(p[q].y) * sc[q];
#pragma unroll
            for (int j = 0; j < 8; ++j) a[j] += w * (float)tv[q][j];
        }
    }
    for (; e < s1; ++e) {
        int2 p = pair[e];
        float w = __int_as_float(p.y) * tscale[p.x];
        s8x8 tv = T[(size_t)p.x * 8 + l8];
#pragma unroll
        for (int j = 0; j < 8; ++j) a[j] += w * (float)tv[j];
    }
    const float4* B2 = (const float4*)b2;
    float4 bv0 = B2[l8 * 2], bv1 = B2[l8 * 2 + 1];
    a[0] = a[0] * dv + bv0.x; a[1] = a[1] * dv + bv0.y;
    a[2] = a[2] * dv + bv0.z; a[3] = a[3] * dv + bv0.w;
    a[4] = a[4] * dv + bv1.x; a[5] = a[5] * dv + bv1.y;
    a[6] = a[6] * dv + bv1.z; a[7] = a[7] * dv + bv1.w;
    float m = a[0];
#pragma unroll
    for (int j = 1; j < 8; ++j) m = fmaxf(m, a[j]);
    for (int o = 4; o > 0; o >>= 1) m = fmaxf(m, __shfl_xor(m, o));
    float s = 0.0f;
#pragma unroll
    for (int j = 0; j < 8; ++j) s += __expf(a[j] - m);
    for (int o = 4; o > 0; o >>= 1) s += __shfl_xor(s, o);
    float ls = m + __logf(s);
    f32x4 o0, o1;
    o0[0] = a[0] - ls; o0[1] = a[1] - ls; o0[2] = a[2] - ls; o0[3] = a[3] - ls;
    o1[0] = a[4] - ls; o1[1] = a[5] - ls; o1[2] = a[6] - ls; o1[3] = a[7] - ls;
    f32x4* O = (f32x4*)out;  // row = 16 x f32x4
    O[(size_t)node * 16 + l8 * 2] = o0;
    O[(size_t)node * 16 + l8 * 2 + 1] = o1;
}

extern "C" void kernel_launch(void* const* d_in, const int* in_sizes, int n_in,
                              void* d_out, int out_size, void* d_ws, size_t ws_size,
                              hipStream_t stream) {
    const float* x   = (const float*)d_in[0];
    const int*  edge = (const int*)d_in[1];
    const float* W1  = (const float*)d_in[2];
    const float* b1  = (const float*)d_in[3];
    const float* W2  = (const float*)d_in[4];
    const float* b2  = (const float*)d_in[5];
    float* out = (float*)d_out;

    int n = in_sizes[0] / 256;   // 100000
    int E = in_sizes[1] / 2;     // 3200000
    int NB = (n + 511) >> 9;     // node buckets (512 each); requires n < 131072
    int chunk = (E + NBLK - 1) / NBLK;

    char* ws = (char*)d_ws;
    auto alloc = [&](size_t bytes) -> char* {
        char* p = ws;
        ws += (bytes + 255) & ~(size_t)255;
        return p;
    };
    int*   gcnt   = (int*)alloc((size_t)NBLK * NB * 4);
    int*   bstart = (int*)alloc((size_t)(NB + 1) * 4);
    int*   ebuf   = (int*)alloc((size_t)E * 4);
    float* dinv   = (float*)alloc((size_t)n * 4);
    int*   off    = (int*)alloc((size_t)(n + 1) * 4);
    int2*  pair   = (int2*)alloc((size_t)E * 8);
    s8*    xq     = (s8*)alloc((size_t)n * 256);
    float* scale  = (float*)alloc((size_t)n * 4);
    bf16*  ax     = (bf16*)alloc((size_t)n * 256 * 2);
    bf16*  h1     = (bf16*)alloc((size_t)n * 256 * 2);
    bf16*  tb     = (bf16*)alloc((size_t)n * 64 * 2);
    s8*    tq     = (s8*)alloc((size_t)n * 64);
    float* tscale = (float*)alloc((size_t)n * 4);
    bf16*  W1t    = (bf16*)alloc(256 * 256 * 2);
    bf16*  W2t    = (bf16*)alloc(64 * 256 * 2);

    // --- CSR build (no global atomics) ---
    k_b1<<<NBLK, 256, 0, stream>>>(edge, E, chunk, NB, gcnt);
    k_b2<<<1, 256, 0, stream>>>(gcnt, NB, E, bstart);
    k_b2b<<<NB, 256, 0, stream>>>(gcnt, NB, bstart);
    k_b3<<<NBLK, 256, 0, stream>>>(edge, E, chunk, NB, gcnt, ebuf);
    k_b45<<<NB, 256, 0, stream>>>(ebuf, bstart, n, E, NB, off, dinv);
    k_b6<<<NB, 256, 0, stream>>>(ebuf, bstart, off, dinv, n, pair);

    // --- feature prep ---
    k_quant<<<(n + 3) / 4, 256, 0, stream>>>(x, xq, scale, n);
    k_wt<<<256, 256, 0, stream>>>(W1, W1t, 256);
    k_wt<<<64, 256, 0, stream>>>(W2, W2t, 64);

    // --- layer 1 ---
    k_agg1<<<(n + 7) / 8, 256, 0, stream>>>(xq, scale, off, pair, dinv, ax, n);
    k_gemmp<<<(n + 63) / 64, 256, 0, stream>>>(ax, W1t, b1, h1, n);

    // --- layer 2 ---
    k_gemm2<<<(n + 63) / 64, 256, 0, stream>>>(h1, W2t, tb, n);
    k_quant2<<<(n * 8 + 255) / 256, 256, 0, stream>>>(tb, tq, tscale, n);
    k_agg2<<<(n + 31) / 32, 256, 0, stream>>>(tq, tscale, off, pair, dinv, b2, out, n);
}